// Round 1
// baseline (69.162 us; speedup 1.0000x reference)
//
#include <hip/hip_runtime.h>

// UnPooling3D: input (4,32,32,32,64) f32 -> output (4,64,64,64,64) f32.
// out[b, 2d, 2h, 2w, c] = in[b, d, h, w, c]; all other positions zero.
// Pure memory-bound scatter; single full-output pass with float4 stores.

__global__ __launch_bounds__(256) void unpool3d_kernel(
    const float4* __restrict__ in, float4* __restrict__ out, int n4) {
    const int stride = gridDim.x * blockDim.x;
    for (int i = blockIdx.x * blockDim.x + threadIdx.x; i < n4; i += stride) {
        // i indexes float4s. 16 float4 per output voxel (C=64 floats).
        const int c4    = i & 15;        // which float4 within the channel vector
        const int voxel = i >> 4;        // flat (b, d, h, w) over 64^3 spatial
        const int wo = voxel & 63;
        const int ho = (voxel >> 6) & 63;
        const int dd = (voxel >> 12) & 63;
        const int b  = voxel >> 18;
        float4 v = make_float4(0.f, 0.f, 0.f, 0.f);
        if (((wo | ho | dd) & 1) == 0) {
            // maps to input voxel (b, dd/2, ho/2, wo/2), 32^3 spatial
            const int in_voxel = ((b * 32 + (dd >> 1)) * 32 + (ho >> 1)) * 32 + (wo >> 1);
            v = in[in_voxel * 16 + c4];
        }
        out[i] = v;
    }
}

extern "C" void kernel_launch(void* const* d_in, const int* in_sizes, int n_in,
                              void* d_out, int out_size, void* d_ws, size_t ws_size,
                              hipStream_t stream) {
    const float4* in = (const float4*)d_in[0];
    float4* out = (float4*)d_out;
    const int n4 = out_size / 4;                       // 16,777,216 float4s
    const int block = 256;
    int grid = (n4 + block - 1) / block;
    if (grid > 2048) grid = 2048;                      // grid-stride the rest
    unpool3d_kernel<<<grid, block, 0, stream>>>(in, out, n4);
}

// Round 2
// 52.769 us; speedup vs baseline: 1.3107x; 1.3107x over previous
//
#include <hip/hip_runtime.h>

// UnPooling3D: input (4,32,32,32,64) f32 -> output (4,64,64,64,64) f32.
// out[b, 2d, 2h, 2w, c] = in[b, d, h, w, c]; all other positions zero.
// Memory-bound scatter. Single pass over output; 8x unrolled so 8 loads are
// in flight per thread before the 8 contiguous float4 stores (MLP to hide
// read latency under the write stream).

#define UNROLL 8

__global__ __launch_bounds__(256) void unpool3d_kernel(
    const float4* __restrict__ in, float4* __restrict__ out) {
    const int base = blockIdx.x * (256 * UNROLL) + threadIdx.x;
    float4 v[UNROLL];
#pragma unroll
    for (int k = 0; k < UNROLL; ++k) {
        const int i = base + k * 256;
        const int c4    = i & 15;        // float4 index within 64-channel vector
        const int voxel = i >> 4;        // flat (b, d, h, w) over 64^3 spatial
        const int wo = voxel & 63;
        const int ho = (voxel >> 6) & 63;
        const int dd = (voxel >> 12) & 63;
        const int b  = voxel >> 18;
        v[k] = make_float4(0.f, 0.f, 0.f, 0.f);
        if (((wo | ho | dd) & 1) == 0) {
            const int in_voxel = ((b * 32 + (dd >> 1)) * 32 + (ho >> 1)) * 32 + (wo >> 1);
            v[k] = in[in_voxel * 16 + c4];
        }
    }
#pragma unroll
    for (int k = 0; k < UNROLL; ++k) {
        out[base + k * 256] = v[k];
    }
}

extern "C" void kernel_launch(void* const* d_in, const int* in_sizes, int n_in,
                              void* d_out, int out_size, void* d_ws, size_t ws_size,
                              hipStream_t stream) {
    const float4* in = (const float4*)d_in[0];
    float4* out = (float4*)d_out;
    const int n4 = out_size / 4;                 // 16,777,216 float4s
    const int grid = n4 / (256 * UNROLL);        // 8192 blocks, exact (no tail)
    unpool3d_kernel<<<grid, 256, 0, stream>>>(in, out);
}

// Round 3
// 52.237 us; speedup vs baseline: 1.3240x; 1.0102x over previous
//
#include <hip/hip_runtime.h>

// UnPooling3D: input (4,32,32,32,64) f32 -> output (4,64,64,64,64) f32.
// out[b, 2d, 2h, 2w, c] = in[b, d, h, w, c]; all other positions zero.
// Memory-bound. 8x-unrolled batched loads (MLP) + NON-TEMPORAL stores so the
// 268 MB output write stream doesn't evict the 33.6 MB input from L2/L3 —
// input reads become cache hits across graph replays, HBM traffic ~= writes.

#define UNROLL 8

typedef float f4 __attribute__((ext_vector_type(4)));

__global__ __launch_bounds__(256) void unpool3d_kernel(
    const f4* __restrict__ in, f4* __restrict__ out) {
    const int base = blockIdx.x * (256 * UNROLL) + threadIdx.x;
    f4 v[UNROLL];
#pragma unroll
    for (int k = 0; k < UNROLL; ++k) {
        const int i = base + k * 256;
        const int c4    = i & 15;        // float4 index within 64-channel vector
        const int voxel = i >> 4;        // flat (b, d, h, w) over 64^3 spatial
        const int wo = voxel & 63;
        const int ho = (voxel >> 6) & 63;
        const int dd = (voxel >> 12) & 63;
        const int b  = voxel >> 18;
        v[k] = (f4){0.f, 0.f, 0.f, 0.f};
        if (((wo | ho | dd) & 1) == 0) {
            const int in_voxel = ((b * 32 + (dd >> 1)) * 32 + (ho >> 1)) * 32 + (wo >> 1);
            v[k] = in[in_voxel * 16 + c4];   // cached load — keep input L3-resident
        }
    }
#pragma unroll
    for (int k = 0; k < UNROLL; ++k) {
        __builtin_nontemporal_store(v[k], &out[base + k * 256]);  // nt: evict-first
    }
}

extern "C" void kernel_launch(void* const* d_in, const int* in_sizes, int n_in,
                              void* d_out, int out_size, void* d_ws, size_t ws_size,
                              hipStream_t stream) {
    const f4* in = (const f4*)d_in[0];
    f4* out = (f4*)d_out;
    const int n4 = out_size / 4;                 // 16,777,216 float4s
    const int grid = n4 / (256 * UNROLL);        // 8192 blocks, exact (no tail)
    unpool3d_kernel<<<grid, 256, 0, stream>>>(in, out);
}